// Round 2
// baseline (370.509 us; speedup 1.0000x reference)
//
#include <hip/hip_runtime.h>
#include <hip/hip_bf16.h>

// DCNv2: B=4, C=64, H=W=128, O=64, KS=3, N=9, PAD=1. All I/O float32.
#define BB 4
#define CC 64
#define HH 128
#define WW 128
#define OO 64
#define NN 9
#define HW (HH*WW)
#define HP 130
#define WP 130

// ws layout (float units):
// [0, 15552)      : wpm [tap(9)][c(64)][oc(27)]  (oc<18 -> w_p, else w_m)
// [15552, 15579)  : bias (18 b_p then 9 b_m)
// [15584, 52448)  : wc  [k(9)][c(64)][o(64)]
#define WPM_OFF 0
#define BPM_OFF 15552
#define WC_OFF  15584

__global__ void k_prep(const float* __restrict__ wp,
                       const float* __restrict__ bp,
                       const float* __restrict__ wm,
                       const float* __restrict__ bm,
                       const float* __restrict__ wcv,
                       float* __restrict__ ws) {
    int tid = blockIdx.x * blockDim.x + threadIdx.x;
    if (tid < 15552) {
        int oc = tid % 27;
        int rest = tid / 27;
        int c = rest & 63;
        int t = rest >> 6;
        int dy = t / 3, dx = t % 3;
        float v = (oc < 18) ? wp[((oc * 64 + c) * 3 + dy) * 3 + dx]
                            : wm[(((oc - 18) * 64 + c) * 3 + dy) * 3 + dx];
        ws[tid] = v;
    } else if (tid < 15579) {
        int i = tid - 15552;
        ws[BPM_OFF + i] = (i < 18) ? bp[i] : bm[i - 18];
    } else if (tid >= WC_OFF && tid < WC_OFF + 9 * 64 * 64) {
        int d = tid - WC_OFF;
        int o = d & 63;
        int c = (d >> 6) & 63;
        int k = d >> 12;
        ws[tid] = wcv[(o * 64 + c) * 9 + k];   // w_conv (O,C,3,3) -> [k][c][o]
    }
}

// Fused: per-pixel offset/modulation conv (27 ch) + deformable sampling + einsum.
__global__ void __launch_bounds__(256) k_fused(const float* __restrict__ x,
                                               const float* __restrict__ ws,
                                               float* __restrict__ out) {
    int tid = blockIdx.x * blockDim.x + threadIdx.x;   // B*H*W threads
    int w = tid & 127;
    int h = (tid >> 7) & 127;
    int b = tid >> 14;

    const float* wpm = ws + WPM_OFF;
    const float* bpm = ws + BPM_OFF;
    const float* wc  = ws + WC_OFF;

    const float* xb = x + (size_t)b * (CC * HW);

    // ---- stage 1: 3x3x64 conv -> 27 channels ----
    float a27[27];
#pragma unroll
    for (int i = 0; i < 27; i++) a27[i] = 0.f;

#pragma unroll 1
    for (int t = 0; t < 9; t++) {
        int dy = t / 3, dx = t % 3;
        int ih = h + dy - 1, iw = w + dx - 1;
        bool val = (ih >= 0) && (ih < HH) && (iw >= 0) && (iw < WW);
        int ihc = min(max(ih, 0), HH - 1);
        int iwc = min(max(iw, 0), WW - 1);
        const float* xp = xb + ihc * WW + iwc;
        float mask = val ? 1.f : 0.f;
        const float* wt = wpm + t * 64 * 27;
#pragma unroll 4
        for (int c = 0; c < CC; c++) {
            float xv = xp[c * HW] * mask;
            const float* wr = wt + c * 27;
#pragma unroll
            for (int oc = 0; oc < 27; oc++) a27[oc] += xv * wr[oc];
        }
    }

    // ---- stage 2: 9 deformable taps, bilinear+modulation, einsum ----
    float acc[64];
#pragma unroll
    for (int o = 0; o < 64; o++) acc[o] = 0.f;

#pragma unroll 1
    for (int k = 0; k < 9; k++) {
        int ki = k / 3, kj = k % 3;
        float px = a27[k]      + bpm[k]      + (float)(ki - 1) + (float)(h + 1);
        float py = a27[9 + k]  + bpm[9 + k]  + (float)(kj - 1) + (float)(w + 1);
        float vm = a27[18 + k] + bpm[18 + k];
        float mk = 1.f / (1.f + __expf(-vm));

        float fx = floorf(px), fy = floorf(py);
        float pxc = fminf(fmaxf(px, 0.f), (float)(HP - 1));
        float pyc = fminf(fmaxf(py, 0.f), (float)(WP - 1));
        int qltx = (int)fminf(fmaxf(fx, 0.f), (float)(HP - 1));
        int qlty = (int)fminf(fmaxf(fy, 0.f), (float)(WP - 1));
        int qrbx = (int)fminf(fmaxf(fx + 1.f, 0.f), (float)(HP - 1));
        int qrby = (int)fminf(fmaxf(fy + 1.f, 0.f), (float)(WP - 1));

        float gltx = 1.f + ((float)qltx - pxc);
        float glty = 1.f + ((float)qlty - pyc);
        float grbx = 1.f - ((float)qrbx - pxc);
        float grby = 1.f - ((float)qrby - pyc);

        // zero-padding rows/cols of xp are zeros -> mask those taps
        bool vlx = (qltx >= 1) && (qltx <= HH);
        bool vly = (qlty >= 1) && (qlty <= WW);
        bool vrx = (qrbx >= 1) && (qrbx <= HH);
        bool vry = (qrby >= 1) && (qrby <= WW);
        float g_lt = (vlx && vly) ? gltx * glty * mk : 0.f;
        float g_rb = (vrx && vry) ? grbx * grby * mk : 0.f;
        float g_lb = (vlx && vry) ? gltx * grby * mk : 0.f;
        float g_rt = (vrx && vly) ? grbx * glty * mk : 0.f;

        int xlt = min(max(qltx - 1, 0), HH - 1);
        int ylt = min(max(qlty - 1, 0), WW - 1);
        int xrb = min(max(qrbx - 1, 0), HH - 1);
        int yrb = min(max(qrby - 1, 0), WW - 1);
        int i_lt = xlt * WW + ylt;
        int i_rb = xrb * WW + yrb;
        int i_lb = xlt * WW + yrb;
        int i_rt = xrb * WW + ylt;

        const float* wck = wc + k * 64 * 64;
#pragma unroll 2
        for (int c = 0; c < CC; c++) {
            int cb = c * HW;
            float v = g_lt * xb[cb + i_lt] + g_rb * xb[cb + i_rb]
                    + g_lb * xb[cb + i_lb] + g_rt * xb[cb + i_rt];
            const float* wr = wck + c * 64;
#pragma unroll
            for (int o = 0; o < 64; o++) acc[o] += v * wr[o];
        }
    }

    float* ob = out + (size_t)b * (OO * HW) + h * WW + w;
#pragma unroll
    for (int o = 0; o < 64; o++) ob[(size_t)o * HW] = acc[o];
}

extern "C" void kernel_launch(void* const* d_in, const int* in_sizes, int n_in,
                              void* d_out, int out_size, void* d_ws, size_t ws_size,
                              hipStream_t stream) {
    const float* x   = (const float*)d_in[0];
    const float* wp  = (const float*)d_in[1];
    const float* bp  = (const float*)d_in[2];
    const float* wm  = (const float*)d_in[3];
    const float* bm  = (const float*)d_in[4];
    const float* wcv = (const float*)d_in[5];
    float* ws = (float*)d_ws;
    float* out = (float*)d_out;

    hipLaunchKernelGGL(k_prep, dim3((52448 + 255) / 256), dim3(256), 0, stream,
                       wp, bp, wm, bm, wcv, ws);
    hipLaunchKernelGGL(k_fused, dim3(BB * HW / 256), dim3(256), 0, stream, x, ws, out);
}

// Round 3
// 252.953 us; speedup vs baseline: 1.4647x; 1.4647x over previous
//
#include <hip/hip_runtime.h>
#include <hip/hip_bf16.h>

// DCNv2: B=4, C=64, H=W=128, O=64, KS=3, N=9, PAD=1. I/O float32.
#define BB 4
#define CC 64
#define HH 128
#define WW 128
#define OO 64
#define NN 9
#define HW 16384
#define HP 130
#define WP 130

// ---- ws layout (float-slot offsets) ----
// [0,15552)        wpm fp32 [t(9)][c(64)][oc(27)]
// [15552,15579)    bias fp32 (18 b_p then 9 b_m)
// 15584            wcb  bf16/ushort [o(64)][K(576)], K = kt*64 + c   (36864 ushort)
// 34016            xt   bf16/ushort [b][hw][c]  (4*16384*64 ushort)
// 2131168          px fp32 [b][kt][hw]; +589824 py; +589824 m
#define WPM_OFF 0
#define BPM_OFF 15552
#define WCB_F   15584
#define XT_F    34016
#define PX_OFF  2131168
#define PSZ     589824

typedef __attribute__((ext_vector_type(8))) short s8v;
typedef __attribute__((ext_vector_type(8))) unsigned short u8v;
typedef __attribute__((ext_vector_type(4))) float f4v;

__device__ __forceinline__ unsigned short f2bu(float f) {   // fp32 -> bf16 bits (RNE)
    unsigned int b = __float_as_uint(f);
    return (unsigned short)((b + 0x7FFFu + ((b >> 16) & 1u)) >> 16);
}
__device__ __forceinline__ float bu2f(unsigned short u) {
    return __uint_as_float(((unsigned int)u) << 16);
}

__global__ void k_prep(const float* __restrict__ wp,
                       const float* __restrict__ bp,
                       const float* __restrict__ wm,
                       const float* __restrict__ bm,
                       const float* __restrict__ wcv,
                       float* __restrict__ ws) {
    int tid = blockIdx.x * blockDim.x + threadIdx.x;
    if (tid < 15552) {
        int oc = tid % 27;
        int rest = tid / 27;
        int c = rest & 63;
        int t = rest >> 6;
        int dy = t / 3, dx = t % 3;
        float v = (oc < 18) ? wp[((oc * 64 + c) * 3 + dy) * 3 + dx]
                            : wm[(((oc - 18) * 64 + c) * 3 + dy) * 3 + dx];
        ws[tid] = v;
    } else if (tid < 15579) {
        int i = tid - 15552;
        ws[BPM_OFF + i] = (i < 18) ? bp[i] : bm[i - 18];
    } else if (tid >= 16384 && tid < 16384 + 64 * 576) {
        int d = tid - 16384;
        int o = d / 576;
        int kk = d % 576;          // kk = kt*64 + c
        int kt = kk >> 6;
        int c = kk & 63;
        unsigned short* wcb = (unsigned short*)(ws + WCB_F);
        wcb[o * 576 + kk] = f2bu(wcv[(o * 64 + c) * 9 + kt]);
    }
}

// NCHW fp32 -> NHWC bf16 transpose, 64x64 LDS tiles.
__global__ void __launch_bounds__(256) k_xt(const float* __restrict__ x,
                                            float* __restrict__ ws) {
    __shared__ unsigned short tile[64][66];
    int blk = blockIdx.x;          // 4 b * 256 hw-tiles
    int b = blk >> 8;
    int hw0 = (blk & 255) * 64;
    int t = threadIdx.x;
    unsigned short* xt = (unsigned short*)(ws + XT_F);

#pragma unroll
    for (int p = 0; p < 16; p++) {
        int c = p * 4 + (t >> 6);
        int i = t & 63;
        tile[c][i] = f2bu(x[((size_t)(b * 64 + c)) * HW + hw0 + i]);
    }
    __syncthreads();
#pragma unroll
    for (int p = 0; p < 16; p++) {
        int i = p * 4 + (t >> 6);
        int c = t & 63;
        xt[((size_t)(b * HW + hw0 + i)) * 64 + c] = tile[c][i];
    }
}

// Offset/modulation conv, C split 2-way across threads, LDS reduce.
__global__ void __launch_bounds__(256) k_off(const float* __restrict__ x,
                                             float* __restrict__ ws) {
    __shared__ float red[128 * 27];
    int t = threadIdx.x;
    int pix_local = t & 127;
    int half = t >> 7;
    int pix = blockIdx.x * 128 + pix_local;
    int w = pix & 127;
    int h = (pix >> 7) & 127;
    int b = pix >> 14;

    const float* wpm = ws + WPM_OFF;
    const float* bpm = ws + BPM_OFF;
    const float* xb = x + (size_t)b * (CC * HW);

    float a27[27];
#pragma unroll
    for (int i = 0; i < 27; i++) a27[i] = 0.f;

    int c0 = half * 32;
#pragma unroll 1
    for (int tp = 0; tp < 9; tp++) {
        int dy = tp / 3, dx = tp % 3;
        int ih = h + dy - 1, iw = w + dx - 1;
        bool val = (ih >= 0) && (ih < HH) && (iw >= 0) && (iw < WW);
        int ihc = min(max(ih, 0), HH - 1);
        int iwc = min(max(iw, 0), WW - 1);
        const float* xp = xb + ihc * WW + iwc;
        float mask = val ? 1.f : 0.f;
        const float* wt = wpm + tp * 64 * 27;
#pragma unroll 4
        for (int cc = 0; cc < 32; cc++) {
            int c = c0 + cc;
            float xv = xp[c * HW] * mask;
            const float* wr = wt + c * 27;
#pragma unroll
            for (int oc = 0; oc < 27; oc++) a27[oc] += xv * wr[oc];
        }
    }

    if (half == 1) {
#pragma unroll
        for (int oc = 0; oc < 27; oc++) red[pix_local * 27 + oc] = a27[oc];
    }
    __syncthreads();
    if (half == 0) {
#pragma unroll
        for (int oc = 0; oc < 27; oc++) a27[oc] += red[pix_local * 27 + oc];

        float* pxA = ws + PX_OFF;
        float* pyA = pxA + PSZ;
        float* mmA = pyA + PSZ;
        int hw = pix & 16383;
#pragma unroll
        for (int k = 0; k < 9; k++) {
            int ki = k / 3, kj = k % 3;
            float vx = a27[k] + bpm[k] + (float)(ki - 1) + (float)(h + 1);
            float vy = a27[9 + k] + bpm[9 + k] + (float)(kj - 1) + (float)(w + 1);
            float vm = a27[18 + k] + bpm[18 + k];
            vm = 1.f / (1.f + __expf(-vm));
            size_t o = ((size_t)b * NN + k) * HW + hw;
            pxA[o] = vx;
            pyA[o] = vy;
            mmA[o] = vm;
        }
    }
}

// Fused sampler + MFMA einsum. Workgroup: 64-pixel tile x 64 out channels, K=576.
__global__ void __launch_bounds__(256) k_gemm(const float* __restrict__ ws,
                                              float* __restrict__ out) {
    __shared__ unsigned short Ald[64 * 40];   // Wc tile [m=64][k=32], stride 40
    __shared__ unsigned short Sld[64 * 40];   // S  tile [n=64][k=32], stride 40

    int t = threadIdx.x;
    int lane = t & 63;
    int wid = t >> 6;
    int ln15 = lane & 15;
    int quad = lane >> 4;

    int blk = blockIdx.x;            // 1024: 4 b * 256 tiles
    int b = blk >> 8;
    int hw0 = (blk & 255) * 64;

    const unsigned short* wcb = (const unsigned short*)(ws + WCB_F);
    const unsigned short* xtb = (const unsigned short*)(ws + XT_F) + (size_t)b * HW * 64;
    const float* pxA = ws + PX_OFF;
    const float* pyA = pxA + PSZ;
    const float* mmA = pyA + PSZ;

    int p_loc = t >> 2;              // 0..63  pixel within tile (sampling role)
    int cq = t & 3;                  // 8-channel group within 32-chunk

    f4v acc[4];
#pragma unroll
    for (int mt = 0; mt < 4; mt++) acc[mt] = (f4v){0.f, 0.f, 0.f, 0.f};

#pragma unroll 1
    for (int kt = 0; kt < 9; kt++) {
        // --- bilinear descriptor for (pixel = hw0+p_loc, tap kt) ---
        size_t pidx = ((size_t)b * NN + kt) * HW + hw0 + p_loc;
        float px = pxA[pidx];
        float py = pyA[pidx];
        float mk = mmA[pidx];

        float fx = floorf(px), fy = floorf(py);
        float pxc = fminf(fmaxf(px, 0.f), (float)(HP - 1));
        float pyc = fminf(fmaxf(py, 0.f), (float)(WP - 1));
        int qltx = (int)fminf(fmaxf(fx, 0.f), (float)(HP - 1));
        int qlty = (int)fminf(fmaxf(fy, 0.f), (float)(WP - 1));
        int qrbx = (int)fminf(fmaxf(fx + 1.f, 0.f), (float)(HP - 1));
        int qrby = (int)fminf(fmaxf(fy + 1.f, 0.f), (float)(WP - 1));

        float gltx = 1.f + ((float)qltx - pxc);
        float glty = 1.f + ((float)qlty - pyc);
        float grbx = 1.f - ((float)qrbx - pxc);
        float grby = 1.f - ((float)qrby - pyc);

        bool vlx = (qltx >= 1) && (qltx <= HH);
        bool vly = (qlty >= 1) && (qlty <= WW);
        bool vrx = (qrbx >= 1) && (qrbx <= HH);
        bool vry = (qrby >= 1) && (qrby <= WW);
        float g0 = (vlx && vly) ? gltx * glty * mk : 0.f;   // lt
        float g1 = (vrx && vry) ? grbx * grby * mk : 0.f;   // rb
        float g2 = (vlx && vry) ? gltx * grby * mk : 0.f;   // lb
        float g3 = (vrx && vly) ? grbx * glty * mk : 0.f;   // rt

        int xlt = min(max(qltx - 1, 0), HH - 1);
        int ylt = min(max(qlty - 1, 0), WW - 1);
        int xrb = min(max(qrbx - 1, 0), HH - 1);
        int yrb = min(max(qrby - 1, 0), WW - 1);
        int i0 = xlt * WW + ylt;
        int i1 = xrb * WW + yrb;
        int i2 = xlt * WW + yrb;
        int i3 = xrb * WW + ylt;

#pragma unroll
        for (int ch = 0; ch < 2; ch++) {
            int s = kt * 2 + ch;
            __syncthreads();    // protect previous iteration's LDS reads

            // stage A tile: Wc[m][s*32 .. s*32+32)
            {
                int m = t >> 2, kq = t & 3;
                u8v av = *(const u8v*)(wcb + m * 576 + s * 32 + kq * 8);
                *(u8v*)(&Ald[m * 40 + kq * 8]) = av;
            }
            // sample S tile: channels c = ch*32 + cq*8 .. +8 for pixel p_loc
            {
                int cbase = ch * 32 + cq * 8;
                u8v e0 = *(const u8v*)(xtb + (size_t)i0 * 64 + cbase);
                u8v e1 = *(const u8v*)(xtb + (size_t)i1 * 64 + cbase);
                u8v e2 = *(const u8v*)(xtb + (size_t)i2 * 64 + cbase);
                u8v e3 = *(const u8v*)(xtb + (size_t)i3 * 64 + cbase);
                u8v sv;
#pragma unroll
                for (int j = 0; j < 8; j++) {
                    float v = g0 * bu2f(e0[j]) + g1 * bu2f(e1[j])
                            + g2 * bu2f(e2[j]) + g3 * bu2f(e3[j]);
                    sv[j] = f2bu(v);
                }
                *(u8v*)(&Sld[p_loc * 40 + cq * 8]) = sv;
            }
            __syncthreads();

            // MFMA: B frag = S[n][k], n = wid*16+ln15; A frags = Wc[m][k], 4 m-tiles
            s8v bf = *(const s8v*)(&Sld[(wid * 16 + ln15) * 40 + quad * 8]);
#pragma unroll
            for (int mt = 0; mt < 4; mt++) {
                s8v af = *(const s8v*)(&Ald[(mt * 16 + ln15) * 40 + quad * 8]);
                acc[mt] = __builtin_amdgcn_mfma_f32_16x16x32_bf16(af, bf, acc[mt], 0, 0, 0);
            }
        }
    }

    // epilogue: D[m][n] -> out[b][o][hw0 + wid*16 + ln15], o = mt*16 + quad*4 + r
    int pix = hw0 + wid * 16 + ln15;
    float* ob = out + (size_t)b * (OO * HW) + pix;
#pragma unroll
    for (int mt = 0; mt < 4; mt++) {
#pragma unroll
        for (int r = 0; r < 4; r++) {
            ob[(size_t)(mt * 16 + quad * 4 + r) * HW] = acc[mt][r];
        }
    }
}

extern "C" void kernel_launch(void* const* d_in, const int* in_sizes, int n_in,
                              void* d_out, int out_size, void* d_ws, size_t ws_size,
                              hipStream_t stream) {
    const float* x   = (const float*)d_in[0];
    const float* wp  = (const float*)d_in[1];
    const float* bp  = (const float*)d_in[2];
    const float* wm  = (const float*)d_in[3];
    const float* bm  = (const float*)d_in[4];
    const float* wcv = (const float*)d_in[5];
    float* ws = (float*)d_ws;
    float* out = (float*)d_out;

    hipLaunchKernelGGL(k_prep, dim3(208), dim3(256), 0, stream, wp, bp, wm, bm, wcv, ws);
    hipLaunchKernelGGL(k_xt, dim3(1024), dim3(256), 0, stream, x, ws);
    hipLaunchKernelGGL(k_off, dim3(512), dim3(256), 0, stream, x, ws);
    hipLaunchKernelGGL(k_gemm, dim3(1024), dim3(256), 0, stream, ws, out);
}

// Round 4
// 121.281 us; speedup vs baseline: 3.0550x; 2.0857x over previous
//
#include <hip/hip_runtime.h>
#include <hip/hip_bf16.h>

// DCNv2: B=4, C=64, H=W=128, O=64, KS=3, N=9, PAD=1. I/O float32.
#define BB 4
#define CC 64
#define HH 128
#define WW 128
#define OO 64
#define NN 9
#define HW 16384
#define HP 130
#define WP 130

// ---- ws layout (float-slot offsets) ----
// 0        wpmb bf16 [32][576]   (rows 0..17 w_p, 18..26 w_m, 27..31 zero) = 9216 f
// 9216     bias fp32 (18 b_p then 9 b_m) = 27 f
// 9248     wcb  bf16 [o(64)][K(576)], K = kt*64+c = 18432 f
// 27680    xt   bf16 [b][hw][c] = 2097152 f
// 2124832  px fp32 [b][kt][hw]; +589824 py; +589824 m
#define WPMB_F  0
#define BPM_OFF 9216
#define WCB_F   9248
#define XT_F    27680
#define PX_OFF  2124832
#define PSZ     589824

typedef __attribute__((ext_vector_type(8))) short s8v;
typedef __attribute__((ext_vector_type(8))) unsigned short u8v;
typedef __attribute__((ext_vector_type(4))) float f4v;

__device__ __forceinline__ unsigned short f2bu(float f) {   // fp32 -> bf16 bits (RNE)
    unsigned int b = __float_as_uint(f);
    return (unsigned short)((b + 0x7FFFu + ((b >> 16) & 1u)) >> 16);
}
__device__ __forceinline__ float bu2f(unsigned short u) {
    return __uint_as_float(((unsigned int)u) << 16);
}

__global__ void k_prep(const float* __restrict__ wp,
                       const float* __restrict__ bp,
                       const float* __restrict__ wm,
                       const float* __restrict__ bm,
                       const float* __restrict__ wcv,
                       float* __restrict__ ws) {
    int tid = blockIdx.x * blockDim.x + threadIdx.x;
    if (tid < 18432) {                       // wpmb [32][576]
        int r = tid / 576;
        int kk = tid % 576;                  // kk = kt*64 + c
        int kt = kk >> 6;
        int c = kk & 63;
        int dy = kt / 3, dx = kt % 3;
        float v = 0.f;
        if (r < 18)       v = wp[((r * 64 + c) * 3 + dy) * 3 + dx];
        else if (r < 27)  v = wm[(((r - 18) * 64 + c) * 3 + dy) * 3 + dx];
        ((unsigned short*)(ws + WPMB_F))[tid] = f2bu(v);
    } else if (tid < 18459) {
        int i = tid - 18432;
        ws[BPM_OFF + i] = (i < 18) ? bp[i] : bm[i - 18];
    } else if (tid >= 20480 && tid < 20480 + 36864) {   // wcb [64][576]
        int d = tid - 20480;
        int o = d / 576;
        int kk = d % 576;
        int kt = kk >> 6;
        int c = kk & 63;
        ((unsigned short*)(ws + WCB_F))[o * 576 + kk] = f2bu(wcv[(o * 64 + c) * 9 + kt]);
    }
}

// NCHW fp32 -> NHWC bf16 transpose, 64x64 LDS tiles.
__global__ void __launch_bounds__(256) k_xt(const float* __restrict__ x,
                                            float* __restrict__ ws) {
    __shared__ unsigned short tile[64][66];
    int blk = blockIdx.x;          // 4 b * 256 hw-tiles
    int b = blk >> 8;
    int hw0 = (blk & 255) * 64;
    int t = threadIdx.x;
    unsigned short* xt = (unsigned short*)(ws + XT_F);

#pragma unroll
    for (int p = 0; p < 16; p++) {
        int c = p * 4 + (t >> 6);
        int i = t & 63;
        tile[c][i] = f2bu(x[((size_t)(b * 64 + c)) * HW + hw0 + i]);
    }
    __syncthreads();
#pragma unroll
    for (int p = 0; p < 16; p++) {
        int i = p * 4 + (t >> 6);
        int c = t & 63;
        xt[((size_t)(b * HW + hw0 + i)) * 64 + c] = tile[c][i];
    }
}

// Offset/modulation conv as MFMA GEMM: M=32(27), N=64 pixels/block, K=576.
// B matrix = im2col of xt (shifted NHWC rows, border-masked).
__global__ void __launch_bounds__(256) k_off(const float* __restrict__ ws,
                                             float* __restrict__ wsout) {
    __shared__ unsigned short Awld[32 * 72];   // [oc][k0..64) stride 72
    __shared__ unsigned short Bld[64 * 72];    // [pix][k0..64) stride 72

    int t = threadIdx.x;
    int lane = t & 63;
    int wid = t >> 6;
    int ln15 = lane & 15;
    int quad = lane >> 4;

    int blk = blockIdx.x;          // 1024: 4 b * 256 tiles
    int b = blk >> 8;
    int hw0 = (blk & 255) * 64;

    const unsigned short* wpmb = (const unsigned short*)(ws + WPMB_F);
    const unsigned short* xtb = (const unsigned short*)(ws + XT_F) + (size_t)b * HW * 64;
    const float* bpm = ws + BPM_OFF;

    // staging roles
    int aq_row = t >> 3, aq_g = t & 7;         // A: 32 rows x 8 groups
    int bq_pix = t & 63, bq_half = t >> 6;     // B: 64 pix x 4 ch-groups of 16
    int ph = (hw0 + bq_pix) >> 7;
    int pw = (hw0 + bq_pix) & 127;

    f4v acc[2];
    acc[0] = (f4v){0.f, 0.f, 0.f, 0.f};
    acc[1] = (f4v){0.f, 0.f, 0.f, 0.f};

#pragma unroll 1
    for (int kt = 0; kt < 9; kt++) {
        int dy = kt / 3, dx = kt % 3;
        __syncthreads();
        // stage A: wpmb[32][kt*64 .. +64)
        {
            u8v av = *(const u8v*)(wpmb + aq_row * 576 + kt * 64 + aq_g * 8);
            *(u8v*)(&Awld[aq_row * 72 + aq_g * 8]) = av;
        }
        // stage B: xt row at shifted pixel, 16 ch per thread
        {
            int h2 = ph + dy - 1, w2 = pw + dx - 1;
            bool val = ((unsigned)h2 < 128u) && ((unsigned)w2 < 128u);
            u8v z = (u8v){0, 0, 0, 0, 0, 0, 0, 0};
            u8v e0 = z, e1 = z;
            if (val) {
                const unsigned short* src = xtb + ((size_t)(h2 * 128 + w2)) * 64 + bq_half * 16;
                e0 = *(const u8v*)(src);
                e1 = *(const u8v*)(src + 8);
            }
            *(u8v*)(&Bld[bq_pix * 72 + bq_half * 16]) = e0;
            *(u8v*)(&Bld[bq_pix * 72 + bq_half * 16 + 8]) = e1;
        }
        __syncthreads();

#pragma unroll
        for (int ks = 0; ks < 2; ks++) {
            s8v bf = *(const s8v*)(&Bld[(wid * 16 + ln15) * 72 + ks * 32 + quad * 8]);
#pragma unroll
            for (int mt = 0; mt < 2; mt++) {
                s8v af = *(const s8v*)(&Awld[(mt * 16 + ln15) * 72 + ks * 32 + quad * 8]);
                acc[mt] = __builtin_amdgcn_mfma_f32_16x16x32_bf16(af, bf, acc[mt], 0, 0, 0);
            }
        }
    }

    // epilogue: D col = pixel (wid*16+ln15), row = oc (mt*16 + quad*4 + r)
    int p = hw0 + wid * 16 + ln15;
    int h = p >> 7, w = p & 127;
    float* pxA = wsout + PX_OFF;
    float* pyA = pxA + PSZ;
    float* mmA = pyA + PSZ;
#pragma unroll
    for (int mt = 0; mt < 2; mt++) {
#pragma unroll
        for (int r = 0; r < 4; r++) {
            int oc = mt * 16 + quad * 4 + r;
            if (oc < 27) {
                float v = acc[mt][r] + bpm[oc];
                if (oc < 9) {
                    int ki = oc / 3;
                    pxA[((size_t)b * NN + oc) * HW + p] = v + (float)(ki - 1) + (float)(h + 1);
                } else if (oc < 18) {
                    int k = oc - 9;
                    int kj = k % 3;
                    pyA[((size_t)b * NN + k) * HW + p] = v + (float)(kj - 1) + (float)(w + 1);
                } else {
                    int k = oc - 18;
                    mmA[((size_t)b * NN + k) * HW + p] = 1.f / (1.f + __expf(-v));
                }
            }
        }
    }
}

// Fused sampler + MFMA einsum. 64 pixels x 64 oc per block, K=576, chunk=64/tap.
__global__ void __launch_bounds__(256) k_gemm(const float* __restrict__ ws,
                                              float* __restrict__ out) {
    __shared__ unsigned short Ald[64 * 72];   // Wc [o][k] stride 72
    __shared__ unsigned short Sld[64 * 72];   // S  [pix][k] stride 72

    int t = threadIdx.x;
    int lane = t & 63;
    int wid = t >> 6;
    int ln15 = lane & 15;
    int quad = lane >> 4;

    int blk = blockIdx.x;            // 1024: 4 b * 256 tiles
    int b = blk >> 8;
    int hw0 = (blk & 255) * 64;

    const unsigned short* wcb = (const unsigned short*)(ws + WCB_F);
    const unsigned short* xtb = (const unsigned short*)(ws + XT_F) + (size_t)b * HW * 64;
    const float* pxA = ws + PX_OFF;
    const float* pyA = pxA + PSZ;
    const float* mmA = pyA + PSZ;

    int p_loc = t >> 2;              // pixel within tile (sampling role)
    int cq = t & 3;                  // 16-channel group

    f4v acc[4];
#pragma unroll
    for (int mt = 0; mt < 4; mt++) acc[mt] = (f4v){0.f, 0.f, 0.f, 0.f};

#pragma unroll 1
    for (int kt = 0; kt < 9; kt++) {
        // --- bilinear descriptor for (pixel = hw0+p_loc, tap kt) ---
        size_t pidx = ((size_t)b * NN + kt) * HW + hw0 + p_loc;
        float px = pxA[pidx];
        float py = pyA[pidx];
        float mk = mmA[pidx];

        float fx = floorf(px), fy = floorf(py);
        float pxc = fminf(fmaxf(px, 0.f), (float)(HP - 1));
        float pyc = fminf(fmaxf(py, 0.f), (float)(WP - 1));
        int qltx = (int)fminf(fmaxf(fx, 0.f), (float)(HP - 1));
        int qlty = (int)fminf(fmaxf(fy, 0.f), (float)(WP - 1));
        int qrbx = (int)fminf(fmaxf(fx + 1.f, 0.f), (float)(HP - 1));
        int qrby = (int)fminf(fmaxf(fy + 1.f, 0.f), (float)(WP - 1));

        float gltx = 1.f + ((float)qltx - pxc);
        float glty = 1.f + ((float)qlty - pyc);
        float grbx = 1.f - ((float)qrbx - pxc);
        float grby = 1.f - ((float)qrby - pyc);

        bool vlx = (qltx >= 1) && (qltx <= HH);
        bool vly = (qlty >= 1) && (qlty <= WW);
        bool vrx = (qrbx >= 1) && (qrbx <= HH);
        bool vry = (qrby >= 1) && (qrby <= WW);
        float g0 = (vlx && vly) ? gltx * glty * mk : 0.f;
        float g1 = (vrx && vry) ? grbx * grby * mk : 0.f;
        float g2 = (vlx && vry) ? gltx * grby * mk : 0.f;
        float g3 = (vrx && vly) ? grbx * glty * mk : 0.f;

        int xlt = min(max(qltx - 1, 0), HH - 1);
        int ylt = min(max(qlty - 1, 0), WW - 1);
        int xrb = min(max(qrbx - 1, 0), HH - 1);
        int yrb = min(max(qrby - 1, 0), WW - 1);
        size_t i0 = (size_t)(xlt * WW + ylt) * 64;
        size_t i1 = (size_t)(xrb * WW + yrb) * 64;
        size_t i2 = (size_t)(xlt * WW + yrb) * 64;
        size_t i3 = (size_t)(xrb * WW + ylt) * 64;

        __syncthreads();    // protect previous iteration's LDS reads
        // stage A tile: Wc[row][kt*64 .. +64), 16 ch per thread
        {
            int row = t >> 2, g = t & 3;
            const unsigned short* src = wcb + row * 576 + kt * 64 + g * 16;
            *(u8v*)(&Ald[row * 72 + g * 16]) = *(const u8v*)(src);
            *(u8v*)(&Ald[row * 72 + g * 16 + 8]) = *(const u8v*)(src + 8);
        }
        // sample S tile: 16 channels (cq*16..) for pixel p_loc
        {
            int cbase = cq * 16;
            const unsigned short* s0 = xtb + i0 + cbase;
            const unsigned short* s1 = xtb + i1 + cbase;
            const unsigned short* s2 = xtb + i2 + cbase;
            const unsigned short* s3 = xtb + i3 + cbase;
            u8v e0a = *(const u8v*)(s0), e0b = *(const u8v*)(s0 + 8);
            u8v e1a = *(const u8v*)(s1), e1b = *(const u8v*)(s1 + 8);
            u8v e2a = *(const u8v*)(s2), e2b = *(const u8v*)(s2 + 8);
            u8v e3a = *(const u8v*)(s3), e3b = *(const u8v*)(s3 + 8);
            u8v sva, svb;
#pragma unroll
            for (int j = 0; j < 8; j++) {
                float va = g0 * bu2f(e0a[j]) + g1 * bu2f(e1a[j])
                         + g2 * bu2f(e2a[j]) + g3 * bu2f(e3a[j]);
                float vb = g0 * bu2f(e0b[j]) + g1 * bu2f(e1b[j])
                         + g2 * bu2f(e2b[j]) + g3 * bu2f(e3b[j]);
                sva[j] = f2bu(va);
                svb[j] = f2bu(vb);
            }
            *(u8v*)(&Sld[p_loc * 72 + cbase]) = sva;
            *(u8v*)(&Sld[p_loc * 72 + cbase + 8]) = svb;
        }
        __syncthreads();

#pragma unroll
        for (int ks = 0; ks < 2; ks++) {
            s8v bf = *(const s8v*)(&Sld[(wid * 16 + ln15) * 72 + ks * 32 + quad * 8]);
#pragma unroll
            for (int mt = 0; mt < 4; mt++) {
                s8v af = *(const s8v*)(&Ald[(mt * 16 + ln15) * 72 + ks * 32 + quad * 8]);
                acc[mt] = __builtin_amdgcn_mfma_f32_16x16x32_bf16(af, bf, acc[mt], 0, 0, 0);
            }
        }
    }

    // epilogue: D col = pixel, row = oc
    int pix = hw0 + wid * 16 + ln15;
    float* ob = out + (size_t)b * (OO * HW) + pix;
#pragma unroll
    for (int mt = 0; mt < 4; mt++) {
#pragma unroll
        for (int r = 0; r < 4; r++) {
            ob[(size_t)(mt * 16 + quad * 4 + r) * HW] = acc[mt][r];
        }
    }
}

extern "C" void kernel_launch(void* const* d_in, const int* in_sizes, int n_in,
                              void* d_out, int out_size, void* d_ws, size_t ws_size,
                              hipStream_t stream) {
    const float* x   = (const float*)d_in[0];
    const float* wp  = (const float*)d_in[1];
    const float* bp  = (const float*)d_in[2];
    const float* wm  = (const float*)d_in[3];
    const float* bm  = (const float*)d_in[4];
    const float* wcv = (const float*)d_in[5];
    float* ws = (float*)d_ws;
    float* out = (float*)d_out;

    hipLaunchKernelGGL(k_prep, dim3(224), dim3(256), 0, stream, wp, bp, wm, bm, wcv, ws);
    hipLaunchKernelGGL(k_xt, dim3(1024), dim3(256), 0, stream, x, ws);
    hipLaunchKernelGGL(k_off, dim3(1024), dim3(256), 0, stream, ws, ws);
    hipLaunchKernelGGL(k_gemm, dim3(1024), dim3(256), 0, stream, ws, out);
}